// Round 4
// baseline (1552.761 us; speedup 1.0000x reference)
//
#include <hip/hip_runtime.h>

typedef __attribute__((ext_vector_type(8))) short bf16x8;
typedef __attribute__((ext_vector_type(4))) float f32x4;
typedef __attribute__((ext_vector_type(2))) float f32x2;
typedef __attribute__((ext_vector_type(2))) unsigned int u32x2;

#define DEV static __device__ __forceinline__

DEV unsigned short f2bf(float x){
  unsigned u = __float_as_uint(x);
  u += 0x7fffu + ((u >> 16) & 1u);
  return (unsigned short)(u >> 16);
}
DEV float bf2f(unsigned short b){ return __uint_as_float(((unsigned)b) << 16); }

DEV f32x4 mfma16(bf16x8 a, bf16x8 b, f32x4 c){
  return __builtin_amdgcn_mfma_f32_16x16x32_bf16(a, b, c, 0, 0, 0);
}

// ---------------- staging (256 threads, tile 128 rows x 64 k, LINEAR [128][64] bf16) ----------------

// f32 k-contiguous source -> hi/lo bf16 split planes
DEV void stage_f32_split(char* Lhi, char* Llo, const float* src, int lda, int tid){
#pragma unroll
  for (int i = 0; i < 8; ++i){
    int chunk = i * 256 + tid;
    int row = chunk >> 4;
    int c4 = (chunk & 15) << 2;
    f32x4 v = *(const f32x4*)(src + (size_t)row * lda + c4);
    unsigned short h0 = f2bf(v[0]), h1 = f2bf(v[1]), h2 = f2bf(v[2]), h3 = f2bf(v[3]);
    unsigned short l0 = f2bf(v[0] - bf2f(h0)), l1 = f2bf(v[1] - bf2f(h1));
    unsigned short l2 = f2bf(v[2] - bf2f(h2)), l3 = f2bf(v[3] - bf2f(h3));
    u32x2 hw, lw;
    hw[0] = (unsigned)h0 | ((unsigned)h1 << 16); hw[1] = (unsigned)h2 | ((unsigned)h3 << 16);
    lw[0] = (unsigned)l0 | ((unsigned)l1 << 16); lw[1] = (unsigned)l2 | ((unsigned)l3 << 16);
    int off = row * 128 + (c4 << 1);
    *(u32x2*)(Lhi + off) = hw;
    *(u32x2*)(Llo + off) = lw;
  }
}

// f32 k-contiguous source -> single bf16 plane (no split)
DEV void stage_f32_plain(char* L, const float* src, int lda, int tid){
#pragma unroll
  for (int i = 0; i < 8; ++i){
    int chunk = i * 256 + tid;
    int row = chunk >> 4;
    int c4 = (chunk & 15) << 2;
    f32x4 v = *(const f32x4*)(src + (size_t)row * lda + c4);
    u32x2 hw;
    hw[0] = (unsigned)f2bf(v[0]) | ((unsigned)f2bf(v[1]) << 16);
    hw[1] = (unsigned)f2bf(v[2]) | ((unsigned)f2bf(v[3]) << 16);
    *(u32x2*)(L + row * 128 + (c4 << 1)) = hw;
  }
}

// f32 B[k][n] (n contiguous) -> transposed LDS Bt[n][k], optional lo plane
template<bool SPLIT>
DEV void stage_f32_T(char* Lhi, char* Llo, const float* src, int ldb, int tid){
#pragma unroll
  for (int i = 0; i < 8; ++i){
    int mb = i * 256 + tid;
    int np = mb & 63, kp = mb >> 6;
    int gk = kp << 1, gn = np << 1;
    const float* p = src + (size_t)gk * ldb + gn;
    f32x2 r0 = *(const f32x2*)p;
    f32x2 r1 = *(const f32x2*)(p + ldb);
    unsigned short ha = f2bf(r0[0]), hb = f2bf(r1[0]);
    unsigned short hc = f2bf(r0[1]), hd = f2bf(r1[1]);
    *(unsigned*)(Lhi + gn * 128 + (gk << 1))       = (unsigned)ha | ((unsigned)hb << 16);
    *(unsigned*)(Lhi + (gn + 1) * 128 + (gk << 1)) = (unsigned)hc | ((unsigned)hd << 16);
    if (SPLIT){
      unsigned short la = f2bf(r0[0] - bf2f(ha)), lb = f2bf(r1[0] - bf2f(hb));
      unsigned short lc = f2bf(r0[1] - bf2f(hc)), ld = f2bf(r1[1] - bf2f(hd));
      *(unsigned*)(Llo + gn * 128 + (gk << 1))       = (unsigned)la | ((unsigned)lb << 16);
      *(unsigned*)(Llo + (gn + 1) * 128 + (gk << 1)) = (unsigned)lc | ((unsigned)ld << 16);
    }
  }
}

// ---------------- MFMA tile compute (wave tile 64x64, 4x4 frags of 16x16x32) ----------------

DEV void compute_split(f32x4 acc[4][4], const char* Ahi, const char* Alo,
                       const char* Bhi, const char* Blo, int wr, int wc, int lane){
  int lr = lane & 15, lg = lane >> 4;
#pragma unroll
  for (int kk = 0; kk < 2; ++kk){
    int cb = kk * 64 + lg * 16;
    bf16x8 ah[4], al[4], bh[4], bl[4];
#pragma unroll
    for (int m = 0; m < 4; ++m){
      int r = wr * 64 + m * 16 + lr;
      ah[m] = *(const bf16x8*)(Ahi + r * 128 + cb);
      al[m] = *(const bf16x8*)(Alo + r * 128 + cb);
    }
#pragma unroll
    for (int n = 0; n < 4; ++n){
      int r = wc * 64 + n * 16 + lr;
      bh[n] = *(const bf16x8*)(Bhi + r * 128 + cb);
      bl[n] = *(const bf16x8*)(Blo + r * 128 + cb);
    }
#pragma unroll
    for (int m = 0; m < 4; ++m)
#pragma unroll
      for (int n = 0; n < 4; ++n){
        acc[m][n] = mfma16(ah[m], bh[n], acc[m][n]);
        acc[m][n] = mfma16(al[m], bh[n], acc[m][n]);
        acc[m][n] = mfma16(ah[m], bl[n], acc[m][n]);
      }
  }
}

DEV void compute_plain(f32x4 acc[4][4], const char* A, const char* B, int wr, int wc, int lane){
  int lr = lane & 15, lg = lane >> 4;
#pragma unroll
  for (int kk = 0; kk < 2; ++kk){
    int cb = kk * 64 + lg * 16;
    bf16x8 af[4], bf_[4];
#pragma unroll
    for (int m = 0; m < 4; ++m)
      af[m] = *(const bf16x8*)(A + (wr * 64 + m * 16 + lr) * 128 + cb);
#pragma unroll
    for (int n = 0; n < 4; ++n)
      bf_[n] = *(const bf16x8*)(B + (wc * 64 + n * 16 + lr) * 128 + cb);
#pragma unroll
    for (int m = 0; m < 4; ++m)
#pragma unroll
      for (int n = 0; n < 4; ++n)
        acc[m][n] = mfma16(af[m], bf_[n], acc[m][n]);
  }
}

// ---------------- kernel 1: keys = enc @ Wa + bias (split-3 MFMA), f32 out ----------------

__global__ __launch_bounds__(256, 2) void keys_gemm(
    const float* __restrict__ enc, const float* __restrict__ Wa,
    const float* __restrict__ bias, float* __restrict__ keysf)
{
  __shared__ char lds[65536];
  char *Ahi = lds, *Alo = lds + 16384, *Bhi = lds + 32768, *Blo = lds + 49152;
  const int tid = threadIdx.x;
  const int lane = tid & 63, w = tid >> 6;
  const int wr = w >> 1, wc = w & 1;
  const int lr = lane & 15, lg = lane >> 4;
  const int m0 = blockIdx.y * 128;   // rows in [B*S_ENC] = 16384
  const int n0 = blockIdx.x * 128;   // output feature cols (H=1024)

  f32x4 acc[4][4];
#pragma unroll
  for (int m = 0; m < 4; ++m)
#pragma unroll
    for (int n = 0; n < 4; ++n) acc[m][n] = (f32x4){0.f, 0.f, 0.f, 0.f};

  for (int k0 = 0; k0 < 1024; k0 += 64){
    __syncthreads();
    stage_f32_split(Ahi, Alo, enc + (size_t)m0 * 1024 + k0, 1024, tid);
    stage_f32_T<true>(Bhi, Blo, Wa + (size_t)k0 * 1024 + n0, 1024, tid);
    __syncthreads();
    compute_split(acc, Ahi, Alo, Bhi, Blo, wr, wc, lane);
  }

#pragma unroll
  for (int n = 0; n < 4; ++n){
    int col = n0 + wc * 64 + n * 16 + lr;
    float bv = bias[col];
#pragma unroll
    for (int m = 0; m < 4; ++m){
      int rbase = m0 + wr * 64 + m * 16 + lg * 4;
#pragma unroll
      for (int j = 0; j < 4; ++j)
        keysf[(size_t)(rbase + j) * 1024 + col] = acc[m][n][j] + bv;
    }
  }
}

// ---------------- kernel 2: scores = dec @ keys^T (split-3 MFMA), f32 out ----------------

__global__ __launch_bounds__(256, 2) void score_gemm(
    const float* __restrict__ dec, const float* __restrict__ keysf,
    float* __restrict__ scores)
{
  __shared__ char lds[65536];
  char *Ahi = lds, *Alo = lds + 16384, *Bhi = lds + 32768, *Blo = lds + 49152;
  const int tid = threadIdx.x;
  const int lane = tid & 63, w = tid >> 6;
  const int wr = w >> 1, wc = w & 1;
  const int lr = lane & 15, lg = lane >> 4;
  const int b  = blockIdx.z;
  const int m0 = blockIdx.y * 128;   // decoder rows
  const int n0 = blockIdx.x * 128;   // encoder rows

  f32x4 acc[4][4];
#pragma unroll
  for (int m = 0; m < 4; ++m)
#pragma unroll
    for (int n = 0; n < 4; ++n) acc[m][n] = (f32x4){0.f, 0.f, 0.f, 0.f};

  const float* Asrc = dec   + ((size_t)b * 2048 + m0) * 1024;
  const float* Bsrc = keysf + ((size_t)b * 2048 + n0) * 1024;

  for (int k0 = 0; k0 < 1024; k0 += 64){
    __syncthreads();
    stage_f32_split(Ahi, Alo, Asrc + k0, 1024, tid);
    stage_f32_split(Bhi, Blo, Bsrc + k0, 1024, tid);
    __syncthreads();
    compute_split(acc, Ahi, Alo, Bhi, Blo, wr, wc, lane);
  }

#pragma unroll
  for (int n = 0; n < 4; ++n){
    int col = n0 + wc * 64 + n * 16 + lr;
#pragma unroll
    for (int m = 0; m < 4; ++m){
      int rbase = m0 + wr * 64 + m * 16 + lg * 4;
#pragma unroll
      for (int j = 0; j < 4; ++j)
        scores[((size_t)b * 2048 + rbase + j) * 2048 + col] = acc[m][n][j];
    }
  }
}

// ---------------- kernel 3: row softmax over 2048, f32 IN-PLACE ----------------

__global__ __launch_bounds__(256) void softmax_k(float* scores)
{
  const int row = blockIdx.x;          // b*2048 + d
  const int t = threadIdx.x;
  float* src = scores + (size_t)row * 2048;
  f32x4 va = *(const f32x4*)(src + t * 8);
  f32x4 vb = *(const f32x4*)(src + t * 8 + 4);
  float f[8];
#pragma unroll
  for (int j = 0; j < 4; ++j){ f[j] = va[j]; f[4 + j] = vb[j]; }
  float m = -3.0e38f;
#pragma unroll
  for (int j = 0; j < 8; ++j) m = fmaxf(m, f[j]);
#pragma unroll
  for (int o = 1; o < 64; o <<= 1) m = fmaxf(m, __shfl_xor(m, o));
  __shared__ float red[4];
  const int wid = t >> 6;
  if ((t & 63) == 0) red[wid] = m;
  __syncthreads();
  m = fmaxf(fmaxf(red[0], red[1]), fmaxf(red[2], red[3]));
  float p[8]; float s = 0.f;
#pragma unroll
  for (int j = 0; j < 8; ++j){ p[j] = __expf(f[j] - m); s += p[j]; }
#pragma unroll
  for (int o = 1; o < 64; o <<= 1) s += __shfl_xor(s, o);
  __syncthreads();
  if ((t & 63) == 0) red[wid] = s;
  __syncthreads();
  s = (red[0] + red[1]) + (red[2] + red[3]);
  float inv = 1.0f / s;
  f32x4 oa, ob;
#pragma unroll
  for (int j = 0; j < 4; ++j){ oa[j] = p[j] * inv; ob[j] = p[4 + j] * inv; }
  *(f32x4*)(src + t * 8)     = oa;
  *(f32x4*)(src + t * 8 + 4) = ob;
}

// ---------------- kernel 4: context = alignment @ enc (plain bf16 MFMA), f32 out ----------------

__global__ __launch_bounds__(256, 2) void ctx_gemm(
    const float* __restrict__ alignf, const float* __restrict__ enc,
    float* __restrict__ ctx)
{
  __shared__ char lds[32768];
  char *A = lds, *B = lds + 16384;
  const int tid = threadIdx.x;
  const int lane = tid & 63, w = tid >> 6;
  const int wr = w >> 1, wc = w & 1;
  const int lr = lane & 15, lg = lane >> 4;
  const int b  = blockIdx.z;
  const int m0 = blockIdx.y * 128;   // decoder rows
  const int n0 = blockIdx.x * 128;   // hidden cols

  f32x4 acc[4][4];
#pragma unroll
  for (int m = 0; m < 4; ++m)
#pragma unroll
    for (int n = 0; n < 4; ++n) acc[m][n] = (f32x4){0.f, 0.f, 0.f, 0.f};

  const float* Asrc = alignf + ((size_t)b * 2048 + m0) * 2048;

  for (int k0 = 0; k0 < 2048; k0 += 64){
    __syncthreads();
    stage_f32_plain(A, Asrc + k0, 2048, tid);
    stage_f32_T<false>(B, nullptr, enc + ((size_t)b * 2048 + k0) * 1024 + n0, 1024, tid);
    __syncthreads();
    compute_plain(acc, A, B, wr, wc, lane);
  }

#pragma unroll
  for (int n = 0; n < 4; ++n){
    int col = n0 + wc * 64 + n * 16 + lr;
#pragma unroll
    for (int m = 0; m < 4; ++m){
      int rbase = m0 + wr * 64 + m * 16 + lg * 4;
#pragma unroll
      for (int j = 0; j < 4; ++j)
        ctx[((size_t)b * 2048 + rbase + j) * 1024 + col] = acc[m][n][j];
    }
  }
}

// ---------------- launch (fully workspace-free) ----------------
// d_out is FLOAT32: ctx [8,2048,1024] then align [8,2048,2048].
// keys (f32, 67 MB) are parked in the ctx region and overwritten by ctx_gemm last;
// scores (f32) live in the align region and are softmaxed in place.

extern "C" void kernel_launch(void* const* d_in, const int* in_sizes, int n_in,
                              void* d_out, int out_size, void* d_ws, size_t ws_size,
                              hipStream_t stream) {
  const float* enc  = (const float*)d_in[0];
  const float* dec  = (const float*)d_in[1];
  const float* Wa   = (const float*)d_in[2];
  const float* bias = (const float*)d_in[3];

  float* out    = (float*)d_out;
  float* ctx    = out;                               // [8][2048][1024] f32
  float* alignf = out + (size_t)8 * 2048 * 1024;     // [8][2048][2048] f32

  float* keysf  = ctx;     // keys [16384][1024] f32 — parked in ctx region
  float* scores = alignf;  // scores in align region, softmaxed in place

  keys_gemm <<<dim3(8, 128),    256, 0, stream>>>(enc, Wa, bias, keysf);
  score_gemm<<<dim3(16, 16, 8), 256, 0, stream>>>(dec, keysf, scores);
  softmax_k <<<dim3(16384),     256, 0, stream>>>(scores);
  ctx_gemm  <<<dim3(8, 16, 8),  256, 0, stream>>>(alignf, enc, ctx);
}

// Round 5
// 763.117 us; speedup vs baseline: 2.0348x; 2.0348x over previous
//
#include <hip/hip_runtime.h>

typedef __attribute__((ext_vector_type(8))) short bf16x8;
typedef __attribute__((ext_vector_type(4))) float f32x4;
typedef __attribute__((ext_vector_type(2))) float f32x2;
typedef __attribute__((ext_vector_type(4))) unsigned int u32x4;
typedef __attribute__((ext_vector_type(2))) unsigned int u32x2;

#define DEV static __device__ __forceinline__

DEV unsigned short f2bf(float x){
  unsigned u = __float_as_uint(x);
  u += 0x7fffu + ((u >> 16) & 1u);
  return (unsigned short)(u >> 16);
}
DEV float bf2f(unsigned short b){ return __uint_as_float(((unsigned)b) << 16); }

// XOR granule swizzle: spreads the 16B granules of each 128B LDS row so that
// fragment ds_read_b128 (lanes read 16 consecutive rows at one column) lands
// 8 lanes per granule = the b128 minimum service time (conflict-free).
DEV int swzb(int row, int cb){ return cb ^ (((row + (row >> 3)) & 7) << 4); }
DEV int loff(int row, int cb){ return row * 128 + swzb(row, cb); }

DEV f32x4 mfma16(bf16x8 a, bf16x8 b, f32x4 c){
  return __builtin_amdgcn_mfma_f32_16x16x32_bf16(a, b, c, 0, 0, 0);
}

// ---------------- staging (256 threads, tile 128 rows x 64 k bf16) ----------------

// raw bf16 plane copy (k-contiguous source)
DEV void stage_raw(char* L, const unsigned short* src, int lda, int tid){
#pragma unroll
  for (int i = 0; i < 4; ++i){
    int chunk = i * 256 + tid;
    int row = chunk >> 3;
    int c8 = (chunk & 7) << 3;          // elem col (x8)
    u32x4 v = *(const u32x4*)(src + (size_t)row * lda + c8);
    *(u32x4*)(L + row * 128 + swzb(row, c8 << 1)) = v;
  }
}

// f32 k-contiguous source -> hi/lo bf16 split planes
DEV void stage_f32_split(char* Lhi, char* Llo, const float* src, int lda, int tid){
#pragma unroll
  for (int i = 0; i < 8; ++i){
    int chunk = i * 256 + tid;
    int row = chunk >> 4;
    int c4 = (chunk & 15) << 2;
    f32x4 v = *(const f32x4*)(src + (size_t)row * lda + c4);
    unsigned short h0 = f2bf(v[0]), h1 = f2bf(v[1]), h2 = f2bf(v[2]), h3 = f2bf(v[3]);
    unsigned short l0 = f2bf(v[0] - bf2f(h0)), l1 = f2bf(v[1] - bf2f(h1));
    unsigned short l2 = f2bf(v[2] - bf2f(h2)), l3 = f2bf(v[3] - bf2f(h3));
    u32x2 hw, lw;
    hw[0] = (unsigned)h0 | ((unsigned)h1 << 16); hw[1] = (unsigned)h2 | ((unsigned)h3 << 16);
    lw[0] = (unsigned)l0 | ((unsigned)l1 << 16); lw[1] = (unsigned)l2 | ((unsigned)l3 << 16);
    int off = row * 128 + swzb(row, c4 << 1);
    *(u32x2*)(Lhi + off) = hw;
    *(u32x2*)(Llo + off) = lw;
  }
}

// f32 k-contiguous source -> single bf16 plane
DEV void stage_f32_plain(char* L, const float* src, int lda, int tid){
#pragma unroll
  for (int i = 0; i < 8; ++i){
    int chunk = i * 256 + tid;
    int row = chunk >> 4;
    int c4 = (chunk & 15) << 2;
    f32x4 v = *(const f32x4*)(src + (size_t)row * lda + c4);
    u32x2 hw;
    hw[0] = (unsigned)f2bf(v[0]) | ((unsigned)f2bf(v[1]) << 16);
    hw[1] = (unsigned)f2bf(v[2]) | ((unsigned)f2bf(v[3]) << 16);
    *(u32x2*)(L + row * 128 + swzb(row, c4 << 1)) = hw;
  }
}

// fallback: f32 B[k][n] (n contiguous) -> transposed LDS Bt[n][k]
DEV void stage_f32_T(char* L, const float* src, int ldb, int tid){
#pragma unroll
  for (int i = 0; i < 8; ++i){
    int mb = i * 256 + tid;
    int np = mb & 63, kp = mb >> 6;
    int gk = kp << 1, gn = np << 1;
    const float* p = src + (size_t)gk * ldb + gn;
    f32x2 r0 = *(const f32x2*)p;
    f32x2 r1 = *(const f32x2*)(p + ldb);
    unsigned short ha = f2bf(r0[0]), hb = f2bf(r1[0]);
    unsigned short hc = f2bf(r0[1]), hd = f2bf(r1[1]);
    *(unsigned*)(L + gn * 128 + swzb(gn, gk << 1))             = (unsigned)ha | ((unsigned)hb << 16);
    *(unsigned*)(L + (gn + 1) * 128 + swzb(gn + 1, gk << 1))   = (unsigned)hc | ((unsigned)hd << 16);
  }
}

// ---------------- MFMA tile compute (wave tile 64x64, 4x4 frags of 16x16x32) ----------------

DEV void compute_split(f32x4 acc[4][4], const char* Ahi, const char* Alo,
                       const char* Bhi, const char* Blo, int wr, int wc, int lane){
  int lr = lane & 15, lg = lane >> 4;
#pragma unroll
  for (int kk = 0; kk < 2; ++kk){
    int cb = kk * 64 + lg * 16;
    bf16x8 ah[4], al[4], bh[4], bl[4];
#pragma unroll
    for (int m = 0; m < 4; ++m){
      int r = wr * 64 + m * 16 + lr;
      ah[m] = *(const bf16x8*)(Ahi + loff(r, cb));
      al[m] = *(const bf16x8*)(Alo + loff(r, cb));
    }
#pragma unroll
    for (int n = 0; n < 4; ++n){
      int r = wc * 64 + n * 16 + lr;
      bh[n] = *(const bf16x8*)(Bhi + loff(r, cb));
      bl[n] = *(const bf16x8*)(Blo + loff(r, cb));
    }
#pragma unroll
    for (int m = 0; m < 4; ++m)
#pragma unroll
      for (int n = 0; n < 4; ++n){
        acc[m][n] = mfma16(ah[m], bh[n], acc[m][n]);
        acc[m][n] = mfma16(al[m], bh[n], acc[m][n]);
        acc[m][n] = mfma16(ah[m], bl[n], acc[m][n]);
      }
  }
}

DEV void compute_plain(f32x4 acc[4][4], const char* A, const char* B, int wr, int wc, int lane){
  int lr = lane & 15, lg = lane >> 4;
#pragma unroll
  for (int kk = 0; kk < 2; ++kk){
    int cb = kk * 64 + lg * 16;
    bf16x8 af[4], bf_[4];
#pragma unroll
    for (int m = 0; m < 4; ++m)
      af[m] = *(const bf16x8*)(A + loff(wr * 64 + m * 16 + lr, cb));
#pragma unroll
    for (int n = 0; n < 4; ++n)
      bf_[n] = *(const bf16x8*)(B + loff(wc * 64 + n * 16 + lr, cb));
#pragma unroll
    for (int m = 0; m < 4; ++m)
#pragma unroll
      for (int n = 0; n < 4; ++n)
        acc[m][n] = mfma16(af[m], bf_[n], acc[m][n]);
  }
}

// ---------------- prep kernels ----------------

// transpose f32 [R][in_ld] -> bf16 planes [C][out_ld] (hi, optional lo)
template<bool SPLIT>
__global__ __launch_bounds__(256) void transpose_prep(
    const float* __restrict__ in, size_t in_bstride, int in_ld,
    unsigned short* __restrict__ oh, unsigned short* __restrict__ ol,
    size_t out_bstride, int out_ld)
{
  __shared__ float T[64][65];
  const int t = threadIdx.x;
  const int r0 = blockIdx.x * 64, c0 = blockIdx.y * 64;
  const float* src = in + (size_t)blockIdx.z * in_bstride;
#pragma unroll
  for (int i = 0; i < 4; ++i){
    int r = (t >> 4) + i * 16;
    int c = (t & 15) * 4;
    f32x4 v = *(const f32x4*)(src + (size_t)(r0 + r) * in_ld + c0 + c);
#pragma unroll
    for (int j = 0; j < 4; ++j) T[r][c + j] = v[j];
  }
  __syncthreads();
#pragma unroll
  for (int i = 0; i < 4; ++i){
    int c = (t >> 4) + i * 16;     // out row (= in col)
    int r = (t & 15) * 4;          // out col group (= in rows)
    float v0 = T[r][c], v1 = T[r + 1][c], v2 = T[r + 2][c], v3 = T[r + 3][c];
    unsigned short h0 = f2bf(v0), h1 = f2bf(v1), h2 = f2bf(v2), h3 = f2bf(v3);
    u32x2 hw;
    hw[0] = (unsigned)h0 | ((unsigned)h1 << 16);
    hw[1] = (unsigned)h2 | ((unsigned)h3 << 16);
    size_t off = (size_t)blockIdx.z * out_bstride + (size_t)(c0 + c) * out_ld + r0 + r;
    *(u32x2*)(oh + off) = hw;
    if (SPLIT){
      u32x2 lw;
      lw[0] = (unsigned)f2bf(v0 - bf2f(h0)) | ((unsigned)f2bf(v1 - bf2f(h1)) << 16);
      lw[1] = (unsigned)f2bf(v2 - bf2f(h2)) | ((unsigned)f2bf(v3 - bf2f(h3)) << 16);
      *(u32x2*)(ol + off) = lw;
    }
  }
}

// elementwise split f32 -> bf16 hi/lo planes (same layout)
__global__ __launch_bounds__(256) void split_prep(
    const float* __restrict__ in, unsigned short* __restrict__ oh,
    unsigned short* __restrict__ ol)
{
  size_t i = ((size_t)blockIdx.x * 256 + threadIdx.x) * 4;
  f32x4 v = *(const f32x4*)(in + i);
  unsigned short h0 = f2bf(v[0]), h1 = f2bf(v[1]), h2 = f2bf(v[2]), h3 = f2bf(v[3]);
  u32x2 hw, lw;
  hw[0] = (unsigned)h0 | ((unsigned)h1 << 16); hw[1] = (unsigned)h2 | ((unsigned)h3 << 16);
  lw[0] = (unsigned)f2bf(v[0] - bf2f(h0)) | ((unsigned)f2bf(v[1] - bf2f(h1)) << 16);
  lw[1] = (unsigned)f2bf(v[2] - bf2f(h2)) | ((unsigned)f2bf(v[3] - bf2f(h3)) << 16);
  *(u32x2*)(oh + i) = hw;
  *(u32x2*)(ol + i) = lw;
}

// ---------------- kernel 1: keys = enc @ Wa + bias -> bf16 hi/lo planes ----------------

__global__ __launch_bounds__(256, 2) void keys_gemm(
    const float* __restrict__ enc,
    const unsigned short* __restrict__ WaTh, const unsigned short* __restrict__ WaTl,
    const float* __restrict__ bias,
    unsigned short* __restrict__ khi, unsigned short* __restrict__ klo)
{
  __shared__ char lds[65536];
  char *Ahi = lds, *Alo = lds + 16384, *Bhi = lds + 32768, *Blo = lds + 49152;
  const int tid = threadIdx.x;
  const int lane = tid & 63, w = tid >> 6;
  const int wr = w >> 1, wc = w & 1;
  const int lr = lane & 15, lg = lane >> 4;
  const int m0 = blockIdx.y * 128;
  const int n0 = blockIdx.x * 128;

  f32x4 acc[4][4];
#pragma unroll
  for (int m = 0; m < 4; ++m)
#pragma unroll
    for (int n = 0; n < 4; ++n) acc[m][n] = (f32x4){0.f, 0.f, 0.f, 0.f};

  for (int k0 = 0; k0 < 1024; k0 += 64){
    __syncthreads();
    stage_f32_split(Ahi, Alo, enc + (size_t)m0 * 1024 + k0, 1024, tid);
    stage_raw(Bhi, WaTh + (size_t)n0 * 1024 + k0, 1024, tid);
    stage_raw(Blo, WaTl + (size_t)n0 * 1024 + k0, 1024, tid);
    __syncthreads();
    compute_split(acc, Ahi, Alo, Bhi, Blo, wr, wc, lane);
  }

#pragma unroll
  for (int n = 0; n < 4; ++n){
    int col = n0 + wc * 64 + n * 16 + lr;
    float bv = bias[col];
#pragma unroll
    for (int m = 0; m < 4; ++m){
      int rbase = m0 + wr * 64 + m * 16 + lg * 4;
#pragma unroll
      for (int j = 0; j < 4; ++j){
        float v = acc[m][n][j] + bv;
        unsigned short h = f2bf(v);
        size_t idx = (size_t)(rbase + j) * 1024 + col;
        khi[idx] = h;
        klo[idx] = f2bf(v - bf2f(h));
      }
    }
  }
}

// ---------------- kernel 2: scores = dec @ keys^T -> f32 ----------------

template<bool PRESPLIT>
__global__ __launch_bounds__(256, 2) void score_gemm(
    const float* __restrict__ dec,
    const unsigned short* __restrict__ dech, const unsigned short* __restrict__ decl,
    const unsigned short* __restrict__ khi, const unsigned short* __restrict__ klo,
    float* __restrict__ scores)
{
  __shared__ char lds[65536];
  char *Ahi = lds, *Alo = lds + 16384, *Bhi = lds + 32768, *Blo = lds + 49152;
  const int tid = threadIdx.x;
  const int lane = tid & 63, w = tid >> 6;
  const int wr = w >> 1, wc = w & 1;
  const int lr = lane & 15, lg = lane >> 4;
  const int b  = blockIdx.z;
  const int m0 = blockIdx.y * 128;
  const int n0 = blockIdx.x * 128;

  f32x4 acc[4][4];
#pragma unroll
  for (int m = 0; m < 4; ++m)
#pragma unroll
    for (int n = 0; n < 4; ++n) acc[m][n] = (f32x4){0.f, 0.f, 0.f, 0.f};

  const size_t arow = (size_t)b * 2048 + m0;
  const size_t brow = (size_t)b * 2048 + n0;

  for (int k0 = 0; k0 < 1024; k0 += 64){
    __syncthreads();
    if (PRESPLIT){
      stage_raw(Ahi, dech + arow * 1024 + k0, 1024, tid);
      stage_raw(Alo, decl + arow * 1024 + k0, 1024, tid);
    } else {
      stage_f32_split(Ahi, Alo, dec + arow * 1024 + k0, 1024, tid);
    }
    stage_raw(Bhi, khi + brow * 1024 + k0, 1024, tid);
    stage_raw(Blo, klo + brow * 1024 + k0, 1024, tid);
    __syncthreads();
    compute_split(acc, Ahi, Alo, Bhi, Blo, wr, wc, lane);
  }

#pragma unroll
  for (int n = 0; n < 4; ++n){
    int col = n0 + wc * 64 + n * 16 + lr;
#pragma unroll
    for (int m = 0; m < 4; ++m){
      int rbase = m0 + wr * 64 + m * 16 + lg * 4;
#pragma unroll
      for (int j = 0; j < 4; ++j)
        scores[((size_t)b * 2048 + rbase + j) * 2048 + col] = acc[m][n][j];
    }
  }
}

// ---------------- kernel 3: row softmax over 2048, f32 in-place ----------------

__global__ __launch_bounds__(256, 4) void softmax_k(float* scores)
{
  const int row = blockIdx.x;
  const int t = threadIdx.x;
  float* src = scores + (size_t)row * 2048;
  f32x4 va = *(const f32x4*)(src + t * 8);
  f32x4 vb = *(const f32x4*)(src + t * 8 + 4);
  float f[8];
#pragma unroll
  for (int j = 0; j < 4; ++j){ f[j] = va[j]; f[4 + j] = vb[j]; }
  float m = -3.0e38f;
#pragma unroll
  for (int j = 0; j < 8; ++j) m = fmaxf(m, f[j]);
#pragma unroll
  for (int o = 1; o < 64; o <<= 1) m = fmaxf(m, __shfl_xor(m, o));
  __shared__ float red[4];
  const int wid = t >> 6;
  if ((t & 63) == 0) red[wid] = m;
  __syncthreads();
  m = fmaxf(fmaxf(red[0], red[1]), fmaxf(red[2], red[3]));
  float p[8]; float s = 0.f;
#pragma unroll
  for (int j = 0; j < 8; ++j){ p[j] = __expf(f[j] - m); s += p[j]; }
#pragma unroll
  for (int o = 1; o < 64; o <<= 1) s += __shfl_xor(s, o);
  __syncthreads();
  if ((t & 63) == 0) red[wid] = s;
  __syncthreads();
  s = (red[0] + red[1]) + (red[2] + red[3]);
  float inv = 1.0f / s;
  f32x4 oa, ob;
#pragma unroll
  for (int j = 0; j < 4; ++j){ oa[j] = p[j] * inv; ob[j] = p[4 + j] * inv; }
  *(f32x4*)(src + t * 8)     = oa;
  *(f32x4*)(src + t * 8 + 4) = ob;
}

// ---------------- kernel 4: context = alignment @ enc -> f32 ----------------

template<bool TRANS_WS>
__global__ __launch_bounds__(256, 2) void ctx_gemm(
    const float* __restrict__ alignf,
    const float* __restrict__ enc, const unsigned short* __restrict__ encT,
    float* __restrict__ ctx)
{
  __shared__ char lds[32768];
  char *A = lds, *B = lds + 16384;
  const int tid = threadIdx.x;
  const int lane = tid & 63, w = tid >> 6;
  const int wr = w >> 1, wc = w & 1;
  const int lr = lane & 15, lg = lane >> 4;
  const int b  = blockIdx.z;
  const int m0 = blockIdx.y * 128;
  const int n0 = blockIdx.x * 128;

  f32x4 acc[4][4];
#pragma unroll
  for (int m = 0; m < 4; ++m)
#pragma unroll
    for (int n = 0; n < 4; ++n) acc[m][n] = (f32x4){0.f, 0.f, 0.f, 0.f};

  const float* Asrc = alignf + ((size_t)b * 2048 + m0) * 2048;

  for (int k0 = 0; k0 < 2048; k0 += 64){
    __syncthreads();
    stage_f32_plain(A, Asrc + k0, 2048, tid);
    if (TRANS_WS)
      stage_raw(B, encT + (size_t)b * 2097152 + (size_t)n0 * 2048 + k0, 2048, tid);
    else
      stage_f32_T(B, enc + ((size_t)b * 2048 + k0) * 1024 + n0, 1024, tid);
    __syncthreads();
    compute_plain(acc, A, B, wr, wc, lane);
  }

#pragma unroll
  for (int n = 0; n < 4; ++n){
    int col = n0 + wc * 64 + n * 16 + lr;
#pragma unroll
    for (int m = 0; m < 4; ++m){
      int rbase = m0 + wr * 64 + m * 16 + lg * 4;
#pragma unroll
      for (int j = 0; j < 4; ++j)
        ctx[((size_t)b * 2048 + rbase + j) * 1024 + col] = acc[m][n][j];
    }
  }
}

// ---------------- launch ----------------
// d_out (f32): ctx [8,2048,1024] | align [8,2048,2048].
// keys bf16 hi/lo planes parked in the ctx region (exactly 67 MB), overwritten
// by ctx_gemm last. Wa^T bf16 hi/lo planes parked in the align-region tail
// (4 MB), consumed by keys_gemm, then overwritten by score_gemm's scores.
// d_ws (optional, runtime-gated): encT bf16 (33.5 MB) + dec hi/lo (67 MB).

extern "C" void kernel_launch(void* const* d_in, const int* in_sizes, int n_in,
                              void* d_out, int out_size, void* d_ws, size_t ws_size,
                              hipStream_t stream) {
  const float* enc  = (const float*)d_in[0];
  const float* dec  = (const float*)d_in[1];
  const float* Wa   = (const float*)d_in[2];
  const float* bias = (const float*)d_in[3];

  float* out    = (float*)d_out;
  float* ctx    = out;                               // [8][2048][1024] f32
  float* alignf = out + (size_t)8 * 2048 * 1024;     // [8][2048][2048] f32
  float* scores = alignf;

  // keys planes in ctx region
  unsigned short* khi = (unsigned short*)ctx;                  // 16384x1024 bf16
  unsigned short* klo = khi + (size_t)16384 * 1024;

  // Wa^T planes in align tail (last 1,048,576 float slots = 4 MB)
  unsigned short* WaTh = (unsigned short*)(alignf + 32505856);
  unsigned short* WaTl = WaTh + (size_t)1024 * 1024;

  // optional workspace buffers
  const size_t ENCT_B = (size_t)8 * 1024 * 2048 * 2;           // 33,554,432
  const size_t DECP_B = (size_t)8 * 2048 * 1024 * 2;           // 33,554,432 per plane
  bool has_encT = ws_size >= ENCT_B;
  bool has_decp = ws_size >= ENCT_B + 2 * DECP_B;              // 100,663,296
  unsigned short* encT = (unsigned short*)d_ws;
  unsigned short* dech = (unsigned short*)((char*)d_ws + ENCT_B);
  unsigned short* decl = (unsigned short*)((char*)d_ws + ENCT_B + DECP_B);

  // preps
  transpose_prep<true><<<dim3(16, 16, 1), 256, 0, stream>>>(
      Wa, 0, 1024, WaTh, WaTl, 0, 1024);
  if (has_encT)
    transpose_prep<false><<<dim3(32, 16, 8), 256, 0, stream>>>(
        enc, (size_t)2048 * 1024, 1024, encT, nullptr, (size_t)1024 * 2048, 2048);
  if (has_decp)
    split_prep<<<dim3(16384), 256, 0, stream>>>(dec, dech, decl);

  keys_gemm<<<dim3(8, 128), 256, 0, stream>>>(enc, WaTh, WaTl, bias, khi, klo);

  if (has_decp)
    score_gemm<true><<<dim3(16, 16, 8), 256, 0, stream>>>(dec, dech, decl, khi, klo, scores);
  else
    score_gemm<false><<<dim3(16, 16, 8), 256, 0, stream>>>(dec, nullptr, nullptr, khi, klo, scores);

  softmax_k<<<dim3(16384), 256, 0, stream>>>(scores);

  if (has_encT)
    ctx_gemm<true><<<dim3(8, 16, 8), 256, 0, stream>>>(alignf, nullptr, encT, ctx);
  else
    ctx_gemm<false><<<dim3(8, 16, 8), 256, 0, stream>>>(alignf, enc, nullptr, ctx);
}

// Round 6
// 535.961 us; speedup vs baseline: 2.8972x; 1.4238x over previous
//
#include <hip/hip_runtime.h>

typedef __attribute__((ext_vector_type(8))) short bf16x8;
typedef __attribute__((ext_vector_type(4))) float f32x4;
typedef __attribute__((ext_vector_type(2))) float f32x2;
typedef __attribute__((ext_vector_type(4))) unsigned int u32x4;
typedef __attribute__((ext_vector_type(2))) unsigned int u32x2;

#define DEV static __device__ __forceinline__

DEV unsigned short f2bf(float x){
  unsigned u = __float_as_uint(x);
  u += 0x7fffu + ((u >> 16) & 1u);
  return (unsigned short)(u >> 16);
}
DEV float bf2f(unsigned short b){ return __uint_as_float(((unsigned)b) << 16); }

// XOR granule swizzle: conflict-free b128 fragment reads on [128][64] bf16 tiles.
DEV int swzb(int row, int cb){ return cb ^ (((row + (row >> 3)) & 7) << 4); }
DEV int loff(int row, int cb){ return row * 128 + swzb(row, cb); }

DEV f32x4 mfma16(bf16x8 a, bf16x8 b, f32x4 c){
  return __builtin_amdgcn_mfma_f32_16x16x32_bf16(a, b, c, 0, 0, 0);
}

// ---------------- staging (256 threads, tile 128 rows x 64 k bf16) ----------------

DEV void stage_raw(char* L, const unsigned short* src, int lda, int tid){
#pragma unroll
  for (int i = 0; i < 4; ++i){
    int chunk = i * 256 + tid;
    int row = chunk >> 3;
    int c8 = (chunk & 7) << 3;
    u32x4 v = *(const u32x4*)(src + (size_t)row * lda + c8);
    *(u32x4*)(L + row * 128 + swzb(row, c8 << 1)) = v;
  }
}

DEV void stage_f32_split(char* Lhi, char* Llo, const float* src, int lda, int tid){
#pragma unroll
  for (int i = 0; i < 8; ++i){
    int chunk = i * 256 + tid;
    int row = chunk >> 4;
    int c4 = (chunk & 15) << 2;
    f32x4 v = *(const f32x4*)(src + (size_t)row * lda + c4);
    unsigned short h0 = f2bf(v[0]), h1 = f2bf(v[1]), h2 = f2bf(v[2]), h3 = f2bf(v[3]);
    unsigned short l0 = f2bf(v[0] - bf2f(h0)), l1 = f2bf(v[1] - bf2f(h1));
    unsigned short l2 = f2bf(v[2] - bf2f(h2)), l3 = f2bf(v[3] - bf2f(h3));
    u32x2 hw, lw;
    hw[0] = (unsigned)h0 | ((unsigned)h1 << 16); hw[1] = (unsigned)h2 | ((unsigned)h3 << 16);
    lw[0] = (unsigned)l0 | ((unsigned)l1 << 16); lw[1] = (unsigned)l2 | ((unsigned)l3 << 16);
    int off = row * 128 + swzb(row, c4 << 1);
    *(u32x2*)(Lhi + off) = hw;
    *(u32x2*)(Llo + off) = lw;
  }
}

DEV void stage_f32_plain(char* L, const float* src, int lda, int tid){
#pragma unroll
  for (int i = 0; i < 8; ++i){
    int chunk = i * 256 + tid;
    int row = chunk >> 4;
    int c4 = (chunk & 15) << 2;
    f32x4 v = *(const f32x4*)(src + (size_t)row * lda + c4);
    u32x2 hw;
    hw[0] = (unsigned)f2bf(v[0]) | ((unsigned)f2bf(v[1]) << 16);
    hw[1] = (unsigned)f2bf(v[2]) | ((unsigned)f2bf(v[3]) << 16);
    *(u32x2*)(L + row * 128 + swzb(row, c4 << 1)) = hw;
  }
}

DEV void stage_f32_T(char* L, const float* src, int ldb, int tid){
#pragma unroll
  for (int i = 0; i < 8; ++i){
    int mb = i * 256 + tid;
    int np = mb & 63, kp = mb >> 6;
    int gk = kp << 1, gn = np << 1;
    const float* p = src + (size_t)gk * ldb + gn;
    f32x2 r0 = *(const f32x2*)p;
    f32x2 r1 = *(const f32x2*)(p + ldb);
    *(unsigned*)(L + gn * 128 + swzb(gn, gk << 1))           = (unsigned)f2bf(r0[0]) | ((unsigned)f2bf(r1[0]) << 16);
    *(unsigned*)(L + (gn + 1) * 128 + swzb(gn + 1, gk << 1)) = (unsigned)f2bf(r0[1]) | ((unsigned)f2bf(r1[1]) << 16);
  }
}

// ---------------- MFMA tile compute (wave tile 64x64, 4x4 frags of 16x16x32) ----------------

DEV void compute_split(f32x4 acc[4][4], const char* Ahi, const char* Alo,
                       const char* Bhi, const char* Blo, int wr, int wc, int lane){
  int lr = lane & 15, lg = lane >> 4;
#pragma unroll
  for (int kk = 0; kk < 2; ++kk){
    int cb = kk * 64 + lg * 16;
    bf16x8 ah[4], al[4], bh[4], bl[4];
#pragma unroll
    for (int m = 0; m < 4; ++m){
      int r = wr * 64 + m * 16 + lr;
      ah[m] = *(const bf16x8*)(Ahi + loff(r, cb));
      al[m] = *(const bf16x8*)(Alo + loff(r, cb));
    }
#pragma unroll
    for (int n = 0; n < 4; ++n){
      int r = wc * 64 + n * 16 + lr;
      bh[n] = *(const bf16x8*)(Bhi + loff(r, cb));
      bl[n] = *(const bf16x8*)(Blo + loff(r, cb));
    }
#pragma unroll
    for (int m = 0; m < 4; ++m)
#pragma unroll
      for (int n = 0; n < 4; ++n){
        acc[m][n] = mfma16(ah[m], bh[n], acc[m][n]);
        acc[m][n] = mfma16(al[m], bh[n], acc[m][n]);
        acc[m][n] = mfma16(ah[m], bl[n], acc[m][n]);
      }
  }
}

DEV void compute_plain(f32x4 acc[4][4], const char* A, const char* B, int wr, int wc, int lane){
  int lr = lane & 15, lg = lane >> 4;
#pragma unroll
  for (int kk = 0; kk < 2; ++kk){
    int cb = kk * 64 + lg * 16;
    bf16x8 af[4], bf_[4];
#pragma unroll
    for (int m = 0; m < 4; ++m)
      af[m] = *(const bf16x8*)(A + loff(wr * 64 + m * 16 + lr, cb));
#pragma unroll
    for (int n = 0; n < 4; ++n)
      bf_[n] = *(const bf16x8*)(B + loff(wc * 64 + n * 16 + lr, cb));
#pragma unroll
    for (int m = 0; m < 4; ++m)
#pragma unroll
      for (int n = 0; n < 4; ++n)
        acc[m][n] = mfma16(af[m], bf_[n], acc[m][n]);
  }
}

// ---------------- prep kernels ----------------

template<bool SPLIT>
__global__ __launch_bounds__(256) void transpose_prep(
    const float* __restrict__ in, size_t in_bstride, int in_ld,
    unsigned short* __restrict__ oh, unsigned short* __restrict__ ol,
    size_t out_bstride, int out_ld)
{
  __shared__ float T[64][65];
  const int t = threadIdx.x;
  const int r0 = blockIdx.x * 64, c0 = blockIdx.y * 64;
  const float* src = in + (size_t)blockIdx.z * in_bstride;
#pragma unroll
  for (int i = 0; i < 4; ++i){
    int r = (t >> 4) + i * 16;
    int c = (t & 15) * 4;
    f32x4 v = *(const f32x4*)(src + (size_t)(r0 + r) * in_ld + c0 + c);
#pragma unroll
    for (int j = 0; j < 4; ++j) T[r][c + j] = v[j];
  }
  __syncthreads();
#pragma unroll
  for (int i = 0; i < 4; ++i){
    int c = (t >> 4) + i * 16;
    int r = (t & 15) * 4;
    float v0 = T[r][c], v1 = T[r + 1][c], v2 = T[r + 2][c], v3 = T[r + 3][c];
    unsigned short h0 = f2bf(v0), h1 = f2bf(v1), h2 = f2bf(v2), h3 = f2bf(v3);
    u32x2 hw;
    hw[0] = (unsigned)h0 | ((unsigned)h1 << 16);
    hw[1] = (unsigned)h2 | ((unsigned)h3 << 16);
    size_t off = (size_t)blockIdx.z * out_bstride + (size_t)(c0 + c) * out_ld + r0 + r;
    *(u32x2*)(oh + off) = hw;
    if (SPLIT){
      u32x2 lw;
      lw[0] = (unsigned)f2bf(v0 - bf2f(h0)) | ((unsigned)f2bf(v1 - bf2f(h1)) << 16);
      lw[1] = (unsigned)f2bf(v2 - bf2f(h2)) | ((unsigned)f2bf(v3 - bf2f(h3)) << 16);
      *(u32x2*)(ol + off) = lw;
    }
  }
}

__global__ __launch_bounds__(256) void split_prep(
    const float* __restrict__ in, unsigned short* __restrict__ oh,
    unsigned short* __restrict__ ol)
{
  size_t i = ((size_t)blockIdx.x * 256 + threadIdx.x) * 4;
  f32x4 v = *(const f32x4*)(in + i);
  unsigned short h0 = f2bf(v[0]), h1 = f2bf(v[1]), h2 = f2bf(v[2]), h3 = f2bf(v[3]);
  u32x2 hw, lw;
  hw[0] = (unsigned)h0 | ((unsigned)h1 << 16); hw[1] = (unsigned)h2 | ((unsigned)h3 << 16);
  lw[0] = (unsigned)f2bf(v[0] - bf2f(h0)) | ((unsigned)f2bf(v[1] - bf2f(h1)) << 16);
  lw[1] = (unsigned)f2bf(v[2] - bf2f(h2)) | ((unsigned)f2bf(v[3] - bf2f(h3)) << 16);
  *(u32x2*)(oh + i) = hw;
  *(u32x2*)(ol + i) = lw;
}

// ---------------- kernel 1: keys = enc @ Wa + bias -> bf16 hi/lo planes ----------------

__global__ __launch_bounds__(256, 2) void keys_gemm(
    const float* __restrict__ enc,
    const unsigned short* __restrict__ WaTh, const unsigned short* __restrict__ WaTl,
    const float* __restrict__ bias,
    unsigned short* __restrict__ khi, unsigned short* __restrict__ klo)
{
  __shared__ char lds[65536];
  char *Ahi = lds, *Alo = lds + 16384, *Bhi = lds + 32768, *Blo = lds + 49152;
  const int tid = threadIdx.x;
  const int lane = tid & 63, w = tid >> 6;
  const int wr = w >> 1, wc = w & 1;
  const int lr = lane & 15, lg = lane >> 4;
  const int m0 = blockIdx.y * 128;
  const int n0 = blockIdx.x * 128;

  f32x4 acc[4][4];
#pragma unroll
  for (int m = 0; m < 4; ++m)
#pragma unroll
    for (int n = 0; n < 4; ++n) acc[m][n] = (f32x4){0.f, 0.f, 0.f, 0.f};

  for (int k0 = 0; k0 < 1024; k0 += 64){
    __syncthreads();
    stage_f32_split(Ahi, Alo, enc + (size_t)m0 * 1024 + k0, 1024, tid);
    stage_raw(Bhi, WaTh + (size_t)n0 * 1024 + k0, 1024, tid);
    stage_raw(Blo, WaTl + (size_t)n0 * 1024 + k0, 1024, tid);
    __syncthreads();
    compute_split(acc, Ahi, Alo, Bhi, Blo, wr, wc, lane);
  }

#pragma unroll
  for (int n = 0; n < 4; ++n){
    int col = n0 + wc * 64 + n * 16 + lr;
    float bv = bias[col];
#pragma unroll
    for (int m = 0; m < 4; ++m){
      int rbase = m0 + wr * 64 + m * 16 + lg * 4;
#pragma unroll
      for (int j = 0; j < 4; ++j){
        float v = acc[m][n][j] + bv;
        unsigned short h = f2bf(v);
        size_t idx = (size_t)(rbase + j) * 1024 + col;
        khi[idx] = h;
        klo[idx] = f2bf(v - bf2f(h));
      }
    }
  }
}

// ---------------- kernel 2: scores = dec @ keys^T -> f32 ----------------

template<bool PRESPLIT>
__global__ __launch_bounds__(256, 2) void score_gemm(
    const float* __restrict__ dec,
    const unsigned short* __restrict__ dech, const unsigned short* __restrict__ decl,
    const unsigned short* __restrict__ khi, const unsigned short* __restrict__ klo,
    float* __restrict__ scores)
{
  __shared__ char lds[65536];
  char *Ahi = lds, *Alo = lds + 16384, *Bhi = lds + 32768, *Blo = lds + 49152;
  const int tid = threadIdx.x;
  const int lane = tid & 63, w = tid >> 6;
  const int wr = w >> 1, wc = w & 1;
  const int lr = lane & 15, lg = lane >> 4;
  const int b  = blockIdx.z;
  const int m0 = blockIdx.y * 128;
  const int n0 = blockIdx.x * 128;

  f32x4 acc[4][4];
#pragma unroll
  for (int m = 0; m < 4; ++m)
#pragma unroll
    for (int n = 0; n < 4; ++n) acc[m][n] = (f32x4){0.f, 0.f, 0.f, 0.f};

  const size_t arow = (size_t)b * 2048 + m0;
  const size_t brow = (size_t)b * 2048 + n0;

  for (int k0 = 0; k0 < 1024; k0 += 64){
    __syncthreads();
    if (PRESPLIT){
      stage_raw(Ahi, dech + arow * 1024 + k0, 1024, tid);
      stage_raw(Alo, decl + arow * 1024 + k0, 1024, tid);
    } else {
      stage_f32_split(Ahi, Alo, dec + arow * 1024 + k0, 1024, tid);
    }
    stage_raw(Bhi, khi + brow * 1024 + k0, 1024, tid);
    stage_raw(Blo, klo + brow * 1024 + k0, 1024, tid);
    __syncthreads();
    compute_split(acc, Ahi, Alo, Bhi, Blo, wr, wc, lane);
  }

#pragma unroll
  for (int n = 0; n < 4; ++n){
    int col = n0 + wc * 64 + n * 16 + lr;
#pragma unroll
    for (int m = 0; m < 4; ++m){
      int rbase = m0 + wr * 64 + m * 16 + lg * 4;
#pragma unroll
      for (int j = 0; j < 4; ++j)
        scores[((size_t)b * 2048 + rbase + j) * 2048 + col] = acc[m][n][j];
    }
  }
}

// ---------------- kernel 3: row softmax over 2048, f32 in-place (+opt bf16 copy) ----------------

template<bool DUALW>
__global__ __launch_bounds__(256, 4) void softmax_k(float* scores, unsigned short* alignb)
{
  const int row = blockIdx.x;
  const int t = threadIdx.x;
  float* src = scores + (size_t)row * 2048;
  f32x4 va = *(const f32x4*)(src + t * 8);
  f32x4 vb = *(const f32x4*)(src + t * 8 + 4);
  float f[8];
#pragma unroll
  for (int j = 0; j < 4; ++j){ f[j] = va[j]; f[4 + j] = vb[j]; }
  float m = -3.0e38f;
#pragma unroll
  for (int j = 0; j < 8; ++j) m = fmaxf(m, f[j]);
#pragma unroll
  for (int o = 1; o < 64; o <<= 1) m = fmaxf(m, __shfl_xor(m, o));
  __shared__ float red[4];
  const int wid = t >> 6;
  if ((t & 63) == 0) red[wid] = m;
  __syncthreads();
  m = fmaxf(fmaxf(red[0], red[1]), fmaxf(red[2], red[3]));
  float p[8]; float s = 0.f;
#pragma unroll
  for (int j = 0; j < 8; ++j){ p[j] = __expf(f[j] - m); s += p[j]; }
#pragma unroll
  for (int o = 1; o < 64; o <<= 1) s += __shfl_xor(s, o);
  __syncthreads();
  if ((t & 63) == 0) red[wid] = s;
  __syncthreads();
  s = (red[0] + red[1]) + (red[2] + red[3]);
  float inv = 1.0f / s;
  f32x4 oa, ob;
#pragma unroll
  for (int j = 0; j < 4; ++j){ oa[j] = p[j] * inv; ob[j] = p[4 + j] * inv; }
  *(f32x4*)(src + t * 8)     = oa;
  *(f32x4*)(src + t * 8 + 4) = ob;
  if (DUALW){
    u32x4 wv;
#pragma unroll
    for (int j = 0; j < 4; ++j){
      float x0 = (j < 2) ? oa[2 * j] : ob[2 * j - 4];
      float x1 = (j < 2) ? oa[2 * j + 1] : ob[2 * j - 3];
      wv[j] = (unsigned)f2bf(x0) | ((unsigned)f2bf(x1) << 16);
    }
    *(u32x4*)(alignb + (size_t)row * 2048 + t * 8) = wv;
  }
}

// ---------------- kernel 4 (fast): context from bf16 align + encT, prefetched ----------------
// Flat 1D grid of 1024 blocks; n-column = wgid & 7 -> pins each B-column to one
// XCD's L2 (8 columns <-> 8 XCDs round-robin). Reg-staged prefetch of tile t+1
// overlaps HBM latency with MFMA of tile t. 32 KB LDS, 3 blocks/CU.

__global__ __launch_bounds__(256, 3) void ctx_gemm_fast(
    const unsigned short* __restrict__ alignb,
    const unsigned short* __restrict__ encT,
    float* __restrict__ ctx)
{
  __shared__ char lds[32768];
  char *A = lds, *B = lds + 16384;
  const int tid = threadIdx.x;
  const int lane = tid & 63, w = tid >> 6;
  const int wr = w >> 1, wc = w & 1;
  const int lr = lane & 15, lg = lane >> 4;
  const int wg = blockIdx.x;
  const int n0 = (wg & 7) * 128;
  const int m0 = ((wg >> 3) & 15) * 128;
  const int b  = wg >> 7;

  const unsigned short* Asrc = alignb + ((size_t)b * 2048 + m0) * 2048;
  const unsigned short* Bsrc = encT   + (size_t)b * 2097152 + (size_t)n0 * 2048;

  f32x4 acc[4][4];
#pragma unroll
  for (int m = 0; m < 4; ++m)
#pragma unroll
    for (int n = 0; n < 4; ++n) acc[m][n] = (f32x4){0.f, 0.f, 0.f, 0.f};

  const int row_ = tid >> 3;             // 0..31 base rows (4 chunks of 32)
  const int c8_  = (tid & 7) << 3;       // elem col

  u32x4 ra[4], rb[4];
#pragma unroll
  for (int i = 0; i < 4; ++i){
    int row = row_ + i * 32;
    ra[i] = *(const u32x4*)(Asrc + (size_t)row * 2048 + c8_);
    rb[i] = *(const u32x4*)(Bsrc + (size_t)row * 2048 + c8_);
  }

  for (int t = 0; t < 32; ++t){
    __syncthreads();
#pragma unroll
    for (int i = 0; i < 4; ++i){
      int row = row_ + i * 32;
      int off = row * 128 + swzb(row, c8_ << 1);
      *(u32x4*)(A + off) = ra[i];
      *(u32x4*)(B + off) = rb[i];
    }
    __syncthreads();
    if (t + 1 < 32){
      int k0 = (t + 1) * 64;
#pragma unroll
      for (int i = 0; i < 4; ++i){
        int row = row_ + i * 32;
        ra[i] = *(const u32x4*)(Asrc + (size_t)row * 2048 + k0 + c8_);
        rb[i] = *(const u32x4*)(Bsrc + (size_t)row * 2048 + k0 + c8_);
      }
    }
    compute_plain(acc, A, B, wr, wc, lane);
  }

#pragma unroll
  for (int n = 0; n < 4; ++n){
    int col = n0 + wc * 64 + n * 16 + lr;
#pragma unroll
    for (int m = 0; m < 4; ++m){
      int rbase = m0 + wr * 64 + m * 16 + lg * 4;
#pragma unroll
      for (int j = 0; j < 4; ++j)
        ctx[((size_t)b * 2048 + rbase + j) * 1024 + col] = acc[m][n][j];
    }
  }
}

// ---------------- kernel 4 (fallback): context = alignment(f32) @ enc ----------------

template<bool TRANS_WS>
__global__ __launch_bounds__(256, 2) void ctx_gemm(
    const float* __restrict__ alignf,
    const float* __restrict__ enc, const unsigned short* __restrict__ encT,
    float* __restrict__ ctx)
{
  __shared__ char lds[32768];
  char *A = lds, *B = lds + 16384;
  const int tid = threadIdx.x;
  const int lane = tid & 63, w = tid >> 6;
  const int wr = w >> 1, wc = w & 1;
  const int lr = lane & 15, lg = lane >> 4;
  const int b  = blockIdx.z;
  const int m0 = blockIdx.y * 128;
  const int n0 = blockIdx.x * 128;

  f32x4 acc[4][4];
#pragma unroll
  for (int m = 0; m < 4; ++m)
#pragma unroll
    for (int n = 0; n < 4; ++n) acc[m][n] = (f32x4){0.f, 0.f, 0.f, 0.f};

  const float* Asrc = alignf + ((size_t)b * 2048 + m0) * 2048;

  for (int k0 = 0; k0 < 2048; k0 += 64){
    __syncthreads();
    stage_f32_plain(A, Asrc + k0, 2048, tid);
    if (TRANS_WS)
      stage_raw(B, encT + (size_t)b * 2097152 + (size_t)n0 * 2048 + k0, 2048, tid);
    else
      stage_f32_T(B, enc + ((size_t)b * 2048 + k0) * 1024 + n0, 1024, tid);
    __syncthreads();
    compute_plain(acc, A, B, wr, wc, lane);
  }

#pragma unroll
  for (int n = 0; n < 4; ++n){
    int col = n0 + wc * 64 + n * 16 + lr;
#pragma unroll
    for (int m = 0; m < 4; ++m){
      int rbase = m0 + wr * 64 + m * 16 + lg * 4;
#pragma unroll
      for (int j = 0; j < 4; ++j)
        ctx[((size_t)b * 2048 + rbase + j) * 1024 + col] = acc[m][n][j];
    }
  }
}

// ---------------- launch ----------------
// d_out (f32): ctx [8,2048,1024] | align [8,2048,2048].
// keys bf16 hi/lo planes in ctx region (67 MB, overwritten last). Wa^T planes
// in align tail (4 MB, overwritten by scores). d_ws gated tiers:
//   >=  33.5 MB: encT bf16
//   >= 100.7 MB: + alignb bf16 (softmax dual-write -> fast ctx)
//   >= 167.8 MB: + dec hi/lo planes (raw score A-staging)

extern "C" void kernel_launch(void* const* d_in, const int* in_sizes, int n_in,
                              void* d_out, int out_size, void* d_ws, size_t ws_size,
                              hipStream_t stream) {
  const float* enc  = (const float*)d_in[0];
  const float* dec  = (const float*)d_in[1];
  const float* Wa   = (const float*)d_in[2];
  const float* bias = (const float*)d_in[3];

  float* out    = (float*)d_out;
  float* ctx    = out;
  float* alignf = out + (size_t)8 * 2048 * 1024;
  float* scores = alignf;

  unsigned short* khi = (unsigned short*)ctx;
  unsigned short* klo = khi + (size_t)16384 * 1024;

  unsigned short* WaTh = (unsigned short*)(alignf + 32505856);
  unsigned short* WaTl = WaTh + (size_t)1024 * 1024;

  const size_t ENCT_B   = (size_t)8 * 1024 * 2048 * 2;     //  33,554,432
  const size_t ALIGNB_B = (size_t)8 * 2048 * 2048 * 2;     //  67,108,864
  const size_t DECP_B   = (size_t)8 * 2048 * 1024 * 2;     //  33,554,432 per plane
  bool has_encT   = ws_size >= ENCT_B;
  bool has_alignb = ws_size >= ENCT_B + ALIGNB_B;                 // 100,663,296
  bool has_decp   = ws_size >= ENCT_B + ALIGNB_B + 2 * DECP_B;    // 167,772,160
  unsigned short* encT   = (unsigned short*)d_ws;
  unsigned short* alignb = (unsigned short*)((char*)d_ws + ENCT_B);
  unsigned short* dech   = (unsigned short*)((char*)d_ws + ENCT_B + ALIGNB_B);
  unsigned short* decl   = (unsigned short*)((char*)d_ws + ENCT_B + ALIGNB_B + DECP_B);

  transpose_prep<true><<<dim3(16, 16, 1), 256, 0, stream>>>(
      Wa, 0, 1024, WaTh, WaTl, 0, 1024);
  if (has_encT)
    transpose_prep<false><<<dim3(32, 16, 8), 256, 0, stream>>>(
        enc, (size_t)2048 * 1024, 1024, encT, nullptr, (size_t)1024 * 2048, 2048);
  if (has_decp)
    split_prep<<<dim3(16384), 256, 0, stream>>>(dec, dech, decl);

  keys_gemm<<<dim3(8, 128), 256, 0, stream>>>(enc, WaTh, WaTl, bias, khi, klo);

  if (has_decp)
    score_gemm<true><<<dim3(16, 16, 8), 256, 0, stream>>>(dec, dech, decl, khi, klo, scores);
  else
    score_gemm<false><<<dim3(16, 16, 8), 256, 0, stream>>>(dec, nullptr, nullptr, khi, klo, scores);

  if (has_alignb){
    softmax_k<true><<<dim3(16384), 256, 0, stream>>>(scores, alignb);
    ctx_gemm_fast<<<dim3(1024), 256, 0, stream>>>(alignb, encT, ctx);
  } else {
    softmax_k<false><<<dim3(16384), 256, 0, stream>>>(scores, nullptr);
    if (has_encT)
      ctx_gemm<true><<<dim3(8, 16, 8), 256, 0, stream>>>(alignf, nullptr, encT, ctx);
    else
      ctx_gemm<false><<<dim3(8, 16, 8), 256, 0, stream>>>(alignf, enc, nullptr, ctx);
  }
}

// Round 7
// 477.157 us; speedup vs baseline: 3.2542x; 1.1232x over previous
//
#include <hip/hip_runtime.h>

typedef __attribute__((ext_vector_type(8))) short bf16x8;
typedef __attribute__((ext_vector_type(4))) float f32x4;
typedef __attribute__((ext_vector_type(2))) float f32x2;
typedef __attribute__((ext_vector_type(4))) unsigned int u32x4;
typedef __attribute__((ext_vector_type(2))) unsigned int u32x2;

#define DEV static __device__ __forceinline__

DEV unsigned short f2bf(float x){
  unsigned u = __float_as_uint(x);
  u += 0x7fffu + ((u >> 16) & 1u);
  return (unsigned short)(u >> 16);
}
DEV float bf2f(unsigned short b){ return __uint_as_float(((unsigned)b) << 16); }

// XOR granule swizzle (16B granules within a 128B row)
DEV int swz8(int row){ return (row + (row >> 3)) & 7; }
DEV int swzb(int row, int cb){ return cb ^ (swz8(row) << 4); }
DEV int loff(int row, int cb){ return row * 128 + swzb(row, cb); }

DEV f32x4 mfma16(bf16x8 a, bf16x8 b, f32x4 c){
  return __builtin_amdgcn_mfma_f32_16x16x32_bf16(a, b, c, 0, 0, 0);
}

typedef __attribute__((address_space(3))) void lds_vt;
typedef const __attribute__((address_space(1))) void gm_vt;
DEV void gload16(const void* g, void* l){
  __builtin_amdgcn_global_load_lds((gm_vt*)g, (lds_vt*)l, 16, 0, 0);
}

// ============== BIG-TILE PIPELINED GEMM (256x256xK, bf16 planes -> f32 C) ==============
// 512 thr / 8 waves (2x4); wave tile 128x64; M_rep=8, N_rep=4; BK=64.
// LDS 128KB: 2 buffers x (A 32KB + B 32KB). global_load_lds staging with
// inverse-swizzled global source (linear LDS dest), swizzled ds_read_b128.
// Schedule per tile t: [vmcnt(0) (drains stage(t), issued one full tile ago)];
// s_barrier; issue stage(t+1) -> other buffer (freed by compute(t-1), protected
// by this barrier); compute(t). NPAIR=3 expresses the hi/lo split-3 product as
// a virtual K*3 plane-pair sequence.

template<int NPAIR>
__global__ __launch_bounds__(512, 2) void gemm_big(
    const unsigned short* __restrict__ A0p, const unsigned short* __restrict__ A1p,
    const unsigned short* __restrict__ B0p, const unsigned short* __restrict__ B1p,
    int lda, int ldb, int MBLK, int NBLK, int nkt,
    size_t a_bs, size_t b_bs,
    float* __restrict__ C, int ldc, size_t c_bs)
{
  __shared__ char lds[131072];
  const int tid  = threadIdx.x;
  const int w    = tid >> 6;
  const int lane = tid & 63;
  const int wr = w >> 2, wc = w & 3;
  const int lr = lane & 15, lg = lane >> 4;

  // chunked XCD swizzle: contiguous work chunk per XCD (nwg % 8 == 0)
  const int nwg = gridDim.x;
  const int wg  = (blockIdx.x & 7) * (nwg >> 3) + (blockIdx.x >> 3);
  const int per = MBLK * NBLK;
  const int b   = wg / per;
  const int rr  = wg - b * per;
  const int m0  = (rr / NBLK) * 256;
  const int n0  = (rr % NBLK) * 256;

  const unsigned short* Ab0 = A0p + b * a_bs + (size_t)m0 * lda;
  const unsigned short* Ab1 = A1p + b * a_bs + (size_t)m0 * lda;
  const unsigned short* Bb0 = B0p + b * b_bs + (size_t)n0 * ldb;
  const unsigned short* Bb1 = B1p + b * b_bs + (size_t)n0 * ldb;

  const int NT = nkt * NPAIR;
  const int wu = __builtin_amdgcn_readfirstlane(w);
  const int rg = lane >> 3, sl = lane & 7;

  f32x4 acc[8][4];
#pragma unroll
  for (int m = 0; m < 8; ++m)
#pragma unroll
    for (int n = 0; n < 4; ++n) acc[m][n] = (f32x4){0.f, 0.f, 0.f, 0.f};

  auto STAGE = [&](int t, int bufsel){
    int kp, pr;
    if (NPAIR == 3){ kp = t / 3; pr = t - kp * 3; } else { kp = t; pr = 0; }
    const unsigned short* Ap = ((NPAIR == 3) && pr == 1) ? Ab1 : Ab0;
    const unsigned short* Bp = ((NPAIR == 3) && pr == 2) ? Bb1 : Bb0;
    Ap += kp * 64; Bp += kp * 64;
    char* Abuf = lds + bufsel * 65536;
    char* Bbuf = Abuf + 32768;
#pragma unroll
    for (int j = 0; j < 4; ++j){
      int row = wu * 32 + j * 8 + rg;
      int g = sl ^ swz8(row);
      gload16(Ap + (size_t)row * lda + g * 8, Abuf + (wu * 32 + j * 8) * 128);
      gload16(Bp + (size_t)row * ldb + g * 8, Bbuf + (wu * 32 + j * 8) * 128);
    }
  };

  STAGE(0, 0);

  for (int t = 0; t < NT; ++t){
    asm volatile("s_waitcnt vmcnt(0)" ::: "memory");
    __builtin_amdgcn_s_barrier();
    __builtin_amdgcn_sched_barrier(0);
    if (t + 1 < NT) STAGE(t + 1, (t + 1) & 1);
    __builtin_amdgcn_sched_barrier(0);

    const char* Abuf = lds + (t & 1) * 65536;
    const char* Bbuf = Abuf + 32768;
#pragma unroll
    for (int kk = 0; kk < 2; ++kk){
      bf16x8 afr[8], bfr[4];
#pragma unroll
      for (int n = 0; n < 4; ++n){
        int row = wc * 64 + n * 16 + lr;
        int g = (kk * 4 + lg) ^ swz8(row);
        bfr[n] = *(const bf16x8*)(Bbuf + row * 128 + g * 16);
      }
#pragma unroll
      for (int m = 0; m < 8; ++m){
        int row = wr * 128 + m * 16 + lr;
        int g = (kk * 4 + lg) ^ swz8(row);
        afr[m] = *(const bf16x8*)(Abuf + row * 128 + g * 16);
      }
      __builtin_amdgcn_s_setprio(1);
#pragma unroll
      for (int m = 0; m < 8; ++m)
#pragma unroll
        for (int n = 0; n < 4; ++n)
          acc[m][n] = mfma16(afr[m], bfr[n], acc[m][n]);
      __builtin_amdgcn_s_setprio(0);
    }
  }

#pragma unroll
  for (int m = 0; m < 8; ++m){
    int grow = m0 + wr * 128 + m * 16 + lg * 4;
#pragma unroll
    for (int n = 0; n < 4; ++n){
      int gcol = n0 + wc * 64 + n * 16 + lr;
#pragma unroll
      for (int j = 0; j < 4; ++j)
        C[b * c_bs + (size_t)(grow + j) * ldc + gcol] = acc[m][n][j];
    }
  }
}

// ---------------- staging helpers for the legacy 128-tile kernels ----------------

DEV void stage_raw(char* L, const unsigned short* src, int lda, int tid){
#pragma unroll
  for (int i = 0; i < 4; ++i){
    int chunk = i * 256 + tid;
    int row = chunk >> 3;
    int c8 = (chunk & 7) << 3;
    u32x4 v = *(const u32x4*)(src + (size_t)row * lda + c8);
    *(u32x4*)(L + row * 128 + swzb(row, c8 << 1)) = v;
  }
}

DEV void stage_f32_split(char* Lhi, char* Llo, const float* src, int lda, int tid){
#pragma unroll
  for (int i = 0; i < 8; ++i){
    int chunk = i * 256 + tid;
    int row = chunk >> 4;
    int c4 = (chunk & 15) << 2;
    f32x4 v = *(const f32x4*)(src + (size_t)row * lda + c4);
    unsigned short h0 = f2bf(v[0]), h1 = f2bf(v[1]), h2 = f2bf(v[2]), h3 = f2bf(v[3]);
    u32x2 hw, lw;
    hw[0] = (unsigned)h0 | ((unsigned)h1 << 16); hw[1] = (unsigned)h2 | ((unsigned)h3 << 16);
    lw[0] = (unsigned)f2bf(v[0] - bf2f(h0)) | ((unsigned)f2bf(v[1] - bf2f(h1)) << 16);
    lw[1] = (unsigned)f2bf(v[2] - bf2f(h2)) | ((unsigned)f2bf(v[3] - bf2f(h3)) << 16);
    int off = row * 128 + swzb(row, c4 << 1);
    *(u32x2*)(Lhi + off) = hw;
    *(u32x2*)(Llo + off) = lw;
  }
}

DEV void stage_f32_plain(char* L, const float* src, int lda, int tid){
#pragma unroll
  for (int i = 0; i < 8; ++i){
    int chunk = i * 256 + tid;
    int row = chunk >> 4;
    int c4 = (chunk & 15) << 2;
    f32x4 v = *(const f32x4*)(src + (size_t)row * lda + c4);
    u32x2 hw;
    hw[0] = (unsigned)f2bf(v[0]) | ((unsigned)f2bf(v[1]) << 16);
    hw[1] = (unsigned)f2bf(v[2]) | ((unsigned)f2bf(v[3]) << 16);
    *(u32x2*)(L + row * 128 + swzb(row, c4 << 1)) = hw;
  }
}

DEV void stage_f32_T(char* L, const float* src, int ldb, int tid){
#pragma unroll
  for (int i = 0; i < 8; ++i){
    int mb = i * 256 + tid;
    int np = mb & 63, kp = mb >> 6;
    int gk = kp << 1, gn = np << 1;
    const float* p = src + (size_t)gk * ldb + gn;
    f32x2 r0 = *(const f32x2*)p;
    f32x2 r1 = *(const f32x2*)(p + ldb);
    *(unsigned*)(L + gn * 128 + swzb(gn, gk << 1))           = (unsigned)f2bf(r0[0]) | ((unsigned)f2bf(r1[0]) << 16);
    *(unsigned*)(L + (gn + 1) * 128 + swzb(gn + 1, gk << 1)) = (unsigned)f2bf(r0[1]) | ((unsigned)f2bf(r1[1]) << 16);
  }
}

DEV void compute_split(f32x4 acc[4][4], const char* Ahi, const char* Alo,
                       const char* Bhi, const char* Blo, int wr, int wc, int lane){
  int lr = lane & 15, lg = lane >> 4;
#pragma unroll
  for (int kk = 0; kk < 2; ++kk){
    int cb = kk * 64 + lg * 16;
    bf16x8 ah[4], al[4], bh[4], bl[4];
#pragma unroll
    for (int m = 0; m < 4; ++m){
      int r = wr * 64 + m * 16 + lr;
      ah[m] = *(const bf16x8*)(Ahi + loff(r, cb));
      al[m] = *(const bf16x8*)(Alo + loff(r, cb));
    }
#pragma unroll
    for (int n = 0; n < 4; ++n){
      int r = wc * 64 + n * 16 + lr;
      bh[n] = *(const bf16x8*)(Bhi + loff(r, cb));
      bl[n] = *(const bf16x8*)(Blo + loff(r, cb));
    }
#pragma unroll
    for (int m = 0; m < 4; ++m)
#pragma unroll
      for (int n = 0; n < 4; ++n){
        acc[m][n] = mfma16(ah[m], bh[n], acc[m][n]);
        acc[m][n] = mfma16(al[m], bh[n], acc[m][n]);
        acc[m][n] = mfma16(ah[m], bl[n], acc[m][n]);
      }
  }
}

DEV void compute_plain(f32x4 acc[4][4], const char* A, const char* B, int wr, int wc, int lane){
  int lr = lane & 15, lg = lane >> 4;
#pragma unroll
  for (int kk = 0; kk < 2; ++kk){
    int cb = kk * 64 + lg * 16;
    bf16x8 af[4], bf_[4];
#pragma unroll
    for (int m = 0; m < 4; ++m)
      af[m] = *(const bf16x8*)(A + loff(wr * 64 + m * 16 + lr, cb));
#pragma unroll
    for (int n = 0; n < 4; ++n)
      bf_[n] = *(const bf16x8*)(B + loff(wc * 64 + n * 16 + lr, cb));
#pragma unroll
    for (int m = 0; m < 4; ++m)
#pragma unroll
      for (int n = 0; n < 4; ++n)
        acc[m][n] = mfma16(af[m], bf_[n], acc[m][n]);
  }
}

// ---------------- prep kernels ----------------

template<bool SPLIT>
__global__ __launch_bounds__(256) void transpose_prep(
    const float* __restrict__ in, size_t in_bstride, int in_ld,
    unsigned short* __restrict__ oh, unsigned short* __restrict__ ol,
    size_t out_bstride, int out_ld)
{
  __shared__ float T[64][65];
  const int t = threadIdx.x;
  const int r0 = blockIdx.x * 64, c0 = blockIdx.y * 64;
  const float* src = in + (size_t)blockIdx.z * in_bstride;
#pragma unroll
  for (int i = 0; i < 4; ++i){
    int r = (t >> 4) + i * 16;
    int c = (t & 15) * 4;
    f32x4 v = *(const f32x4*)(src + (size_t)(r0 + r) * in_ld + c0 + c);
#pragma unroll
    for (int j = 0; j < 4; ++j) T[r][c + j] = v[j];
  }
  __syncthreads();
#pragma unroll
  for (int i = 0; i < 4; ++i){
    int c = (t >> 4) + i * 16;
    int r = (t & 15) * 4;
    float v0 = T[r][c], v1 = T[r + 1][c], v2 = T[r + 2][c], v3 = T[r + 3][c];
    unsigned short h0 = f2bf(v0), h1 = f2bf(v1), h2 = f2bf(v2), h3 = f2bf(v3);
    u32x2 hw;
    hw[0] = (unsigned)h0 | ((unsigned)h1 << 16);
    hw[1] = (unsigned)h2 | ((unsigned)h3 << 16);
    size_t off = (size_t)blockIdx.z * out_bstride + (size_t)(c0 + c) * out_ld + r0 + r;
    *(u32x2*)(oh + off) = hw;
    if (SPLIT){
      u32x2 lw;
      lw[0] = (unsigned)f2bf(v0 - bf2f(h0)) | ((unsigned)f2bf(v1 - bf2f(h1)) << 16);
      lw[1] = (unsigned)f2bf(v2 - bf2f(h2)) | ((unsigned)f2bf(v3 - bf2f(h3)) << 16);
      *(u32x2*)(ol + off) = lw;
    }
  }
}

__global__ __launch_bounds__(256) void split_prep(
    const float* __restrict__ in, unsigned short* __restrict__ oh,
    unsigned short* __restrict__ ol)
{
  size_t i = ((size_t)blockIdx.x * 256 + threadIdx.x) * 4;
  f32x4 v = *(const f32x4*)(in + i);
  unsigned short h0 = f2bf(v[0]), h1 = f2bf(v[1]), h2 = f2bf(v[2]), h3 = f2bf(v[3]);
  u32x2 hw, lw;
  hw[0] = (unsigned)h0 | ((unsigned)h1 << 16); hw[1] = (unsigned)h2 | ((unsigned)h3 << 16);
  lw[0] = (unsigned)f2bf(v[0] - bf2f(h0)) | ((unsigned)f2bf(v[1] - bf2f(h1)) << 16);
  lw[1] = (unsigned)f2bf(v[2] - bf2f(h2)) | ((unsigned)f2bf(v[3] - bf2f(h3)) << 16);
  *(u32x2*)(oh + i) = hw;
  *(u32x2*)(ol + i) = lw;
}

// ---------------- kernel 1: keys = enc @ Wa + bias -> bf16 hi/lo planes ----------------

__global__ __launch_bounds__(256, 2) void keys_gemm(
    const float* __restrict__ enc,
    const unsigned short* __restrict__ WaTh, const unsigned short* __restrict__ WaTl,
    const float* __restrict__ bias,
    unsigned short* __restrict__ khi, unsigned short* __restrict__ klo)
{
  __shared__ char lds[65536];
  char *Ahi = lds, *Alo = lds + 16384, *Bhi = lds + 32768, *Blo = lds + 49152;
  const int tid = threadIdx.x;
  const int lane = tid & 63, w = tid >> 6;
  const int wr = w >> 1, wc = w & 1;
  const int lr = lane & 15, lg = lane >> 4;
  const int m0 = blockIdx.y * 128;
  const int n0 = blockIdx.x * 128;

  f32x4 acc[4][4];
#pragma unroll
  for (int m = 0; m < 4; ++m)
#pragma unroll
    for (int n = 0; n < 4; ++n) acc[m][n] = (f32x4){0.f, 0.f, 0.f, 0.f};

  for (int k0 = 0; k0 < 1024; k0 += 64){
    __syncthreads();
    stage_f32_split(Ahi, Alo, enc + (size_t)m0 * 1024 + k0, 1024, tid);
    stage_raw(Bhi, WaTh + (size_t)n0 * 1024 + k0, 1024, tid);
    stage_raw(Blo, WaTl + (size_t)n0 * 1024 + k0, 1024, tid);
    __syncthreads();
    compute_split(acc, Ahi, Alo, Bhi, Blo, wr, wc, lane);
  }

#pragma unroll
  for (int n = 0; n < 4; ++n){
    int col = n0 + wc * 64 + n * 16 + lr;
    float bv = bias[col];
#pragma unroll
    for (int m = 0; m < 4; ++m){
      int rbase = m0 + wr * 64 + m * 16 + lg * 4;
#pragma unroll
      for (int j = 0; j < 4; ++j){
        float v = acc[m][n][j] + bv;
        unsigned short h = f2bf(v);
        size_t idx = (size_t)(rbase + j) * 1024 + col;
        khi[idx] = h;
        klo[idx] = f2bf(v - bf2f(h));
      }
    }
  }
}

// ---------------- legacy score kernel (fallback tiers) ----------------

template<bool PRESPLIT>
__global__ __launch_bounds__(256, 2) void score_gemm(
    const float* __restrict__ dec,
    const unsigned short* __restrict__ dech, const unsigned short* __restrict__ decl,
    const unsigned short* __restrict__ khi, const unsigned short* __restrict__ klo,
    float* __restrict__ scores)
{
  __shared__ char lds[65536];
  char *Ahi = lds, *Alo = lds + 16384, *Bhi = lds + 32768, *Blo = lds + 49152;
  const int tid = threadIdx.x;
  const int lane = tid & 63, w = tid >> 6;
  const int wr = w >> 1, wc = w & 1;
  const int lr = lane & 15, lg = lane >> 4;
  const int b  = blockIdx.z;
  const int m0 = blockIdx.y * 128;
  const int n0 = blockIdx.x * 128;

  f32x4 acc[4][4];
#pragma unroll
  for (int m = 0; m < 4; ++m)
#pragma unroll
    for (int n = 0; n < 4; ++n) acc[m][n] = (f32x4){0.f, 0.f, 0.f, 0.f};

  const size_t arow = (size_t)b * 2048 + m0;
  const size_t brow = (size_t)b * 2048 + n0;

  for (int k0 = 0; k0 < 1024; k0 += 64){
    __syncthreads();
    if (PRESPLIT){
      stage_raw(Ahi, dech + arow * 1024 + k0, 1024, tid);
      stage_raw(Alo, decl + arow * 1024 + k0, 1024, tid);
    } else {
      stage_f32_split(Ahi, Alo, dec + arow * 1024 + k0, 1024, tid);
    }
    stage_raw(Bhi, khi + brow * 1024 + k0, 1024, tid);
    stage_raw(Blo, klo + brow * 1024 + k0, 1024, tid);
    __syncthreads();
    compute_split(acc, Ahi, Alo, Bhi, Blo, wr, wc, lane);
  }

#pragma unroll
  for (int n = 0; n < 4; ++n){
    int col = n0 + wc * 64 + n * 16 + lr;
#pragma unroll
    for (int m = 0; m < 4; ++m){
      int rbase = m0 + wr * 64 + m * 16 + lg * 4;
#pragma unroll
      for (int j = 0; j < 4; ++j)
        scores[((size_t)b * 2048 + rbase + j) * 2048 + col] = acc[m][n][j];
    }
  }
}

// ---------------- softmax ----------------

template<bool DUALW>
__global__ __launch_bounds__(256, 4) void softmax_k(float* scores, unsigned short* alignb)
{
  const int row = blockIdx.x;
  const int t = threadIdx.x;
  float* src = scores + (size_t)row * 2048;
  f32x4 va = *(const f32x4*)(src + t * 8);
  f32x4 vb = *(const f32x4*)(src + t * 8 + 4);
  float f[8];
#pragma unroll
  for (int j = 0; j < 4; ++j){ f[j] = va[j]; f[4 + j] = vb[j]; }
  float m = -3.0e38f;
#pragma unroll
  for (int j = 0; j < 8; ++j) m = fmaxf(m, f[j]);
#pragma unroll
  for (int o = 1; o < 64; o <<= 1) m = fmaxf(m, __shfl_xor(m, o));
  __shared__ float red[4];
  const int wid = t >> 6;
  if ((t & 63) == 0) red[wid] = m;
  __syncthreads();
  m = fmaxf(fmaxf(red[0], red[1]), fmaxf(red[2], red[3]));
  float p[8]; float s = 0.f;
#pragma unroll
  for (int j = 0; j < 8; ++j){ p[j] = __expf(f[j] - m); s += p[j]; }
#pragma unroll
  for (int o = 1; o < 64; o <<= 1) s += __shfl_xor(s, o);
  __syncthreads();
  if ((t & 63) == 0) red[wid] = s;
  __syncthreads();
  s = (red[0] + red[1]) + (red[2] + red[3]);
  float inv = 1.0f / s;
  f32x4 oa, ob;
#pragma unroll
  for (int j = 0; j < 4; ++j){ oa[j] = p[j] * inv; ob[j] = p[4 + j] * inv; }
  *(f32x4*)(src + t * 8)     = oa;
  *(f32x4*)(src + t * 8 + 4) = ob;
  if (DUALW){
    u32x4 wv;
#pragma unroll
    for (int j = 0; j < 4; ++j){
      float x0 = (j < 2) ? oa[2 * j] : ob[2 * j - 4];
      float x1 = (j < 2) ? oa[2 * j + 1] : ob[2 * j - 3];
      wv[j] = (unsigned)f2bf(x0) | ((unsigned)f2bf(x1) << 16);
    }
    *(u32x4*)(alignb + (size_t)row * 2048 + t * 8) = wv;
  }
}

// ---------------- legacy ctx kernels (fallback tiers) ----------------

__global__ __launch_bounds__(256, 3) void ctx_gemm_fast(
    const unsigned short* __restrict__ alignb,
    const unsigned short* __restrict__ encT,
    float* __restrict__ ctx)
{
  __shared__ char lds[32768];
  char *A = lds, *B = lds + 16384;
  const int tid = threadIdx.x;
  const int lane = tid & 63, w = tid >> 6;
  const int wr = w >> 1, wc = w & 1;
  const int lr = lane & 15, lg = lane >> 4;
  const int wg = blockIdx.x;
  const int n0 = (wg & 7) * 128;
  const int m0 = ((wg >> 3) & 15) * 128;
  const int b  = wg >> 7;

  const unsigned short* Asrc = alignb + ((size_t)b * 2048 + m0) * 2048;
  const unsigned short* Bsrc = encT   + (size_t)b * 2097152 + (size_t)n0 * 2048;

  f32x4 acc[4][4];
#pragma unroll
  for (int m = 0; m < 4; ++m)
#pragma unroll
    for (int n = 0; n < 4; ++n) acc[m][n] = (f32x4){0.f, 0.f, 0.f, 0.f};

  const int row_ = tid >> 3;
  const int c8_  = (tid & 7) << 3;

  u32x4 ra[4], rb[4];
#pragma unroll
  for (int i = 0; i < 4; ++i){
    int row = row_ + i * 32;
    ra[i] = *(const u32x4*)(Asrc + (size_t)row * 2048 + c8_);
    rb[i] = *(const u32x4*)(Bsrc + (size_t)row * 2048 + c8_);
  }

  for (int t = 0; t < 32; ++t){
    __syncthreads();
#pragma unroll
    for (int i = 0; i < 4; ++i){
      int row = row_ + i * 32;
      int off = row * 128 + swzb(row, c8_ << 1);
      *(u32x4*)(A + off) = ra[i];
      *(u32x4*)(B + off) = rb[i];
    }
    __syncthreads();
    if (t + 1 < 32){
      int k0 = (t + 1) * 64;
#pragma unroll
      for (int i = 0; i < 4; ++i){
        int row = row_ + i * 32;
        ra[i] = *(const u32x4*)(Asrc + (size_t)row * 2048 + k0 + c8_);
        rb[i] = *(const u32x4*)(Bsrc + (size_t)row * 2048 + k0 + c8_);
      }
    }
    compute_plain(acc, A, B, wr, wc, lane);
  }

#pragma unroll
  for (int n = 0; n < 4; ++n){
    int col = n0 + wc * 64 + n * 16 + lr;
#pragma unroll
    for (int m = 0; m < 4; ++m){
      int rbase = m0 + wr * 64 + m * 16 + lg * 4;
#pragma unroll
      for (int j = 0; j < 4; ++j)
        ctx[((size_t)b * 2048 + rbase + j) * 1024 + col] = acc[m][n][j];
    }
  }
}

template<bool TRANS_WS>
__global__ __launch_bounds__(256, 2) void ctx_gemm(
    const float* __restrict__ alignf,
    const float* __restrict__ enc, const unsigned short* __restrict__ encT,
    float* __restrict__ ctx)
{
  __shared__ char lds[32768];
  char *A = lds, *B = lds + 16384;
  const int tid = threadIdx.x;
  const int lane = tid & 63, w = tid >> 6;
  const int wr = w >> 1, wc = w & 1;
  const int lr = lane & 15, lg = lane >> 4;
  const int b  = blockIdx.z;
  const int m0 = blockIdx.y * 128;
  const int n0 = blockIdx.x * 128;

  f32x4 acc[4][4];
#pragma unroll
  for (int m = 0; m < 4; ++m)
#pragma unroll
    for (int n = 0; n < 4; ++n) acc[m][n] = (f32x4){0.f, 0.f, 0.f, 0.f};

  const float* Asrc = alignf + ((size_t)b * 2048 + m0) * 2048;

  for (int k0 = 0; k0 < 2048; k0 += 64){
    __syncthreads();
    stage_f32_plain(A, Asrc + k0, 2048, tid);
    if (TRANS_WS)
      stage_raw(B, encT + (size_t)b * 2097152 + (size_t)n0 * 2048 + k0, 2048, tid);
    else
      stage_f32_T(B, enc + ((size_t)b * 2048 + k0) * 1024 + n0, 1024, tid);
    __syncthreads();
    compute_plain(acc, A, B, wr, wc, lane);
  }

#pragma unroll
  for (int n = 0; n < 4; ++n){
    int col = n0 + wc * 64 + n * 16 + lr;
#pragma unroll
    for (int m = 0; m < 4; ++m){
      int rbase = m0 + wr * 64 + m * 16 + lg * 4;
#pragma unroll
      for (int j = 0; j < 4; ++j)
        ctx[((size_t)b * 2048 + rbase + j) * 1024 + col] = acc[m][n][j];
    }
  }
}

// ---------------- launch ----------------
// d_out (f32): ctx [8,2048,1024] | align [8,2048,2048].
// keys bf16 hi/lo planes in ctx region (67 MB, overwritten last). Wa^T planes
// in align tail (4 MB, overwritten by scores). d_ws tiers:
//   >=  33.5 MB: encT bf16
//   >= 100.7 MB: + alignb bf16
//   >= 167.8 MB: + dec hi/lo planes -> big-tile pipelined score & ctx

extern "C" void kernel_launch(void* const* d_in, const int* in_sizes, int n_in,
                              void* d_out, int out_size, void* d_ws, size_t ws_size,
                              hipStream_t stream) {
  const float* enc  = (const float*)d_in[0];
  const float* dec  = (const float*)d_in[1];
  const float* Wa   = (const float*)d_in[2];
  const float* bias = (const float*)d_in[3];

  float* out    = (float*)d_out;
  float* ctx    = out;
  float* alignf = out + (size_t)8 * 2048 * 1024;
  float* scores = alignf;

  unsigned short* khi = (unsigned short*)ctx;
  unsigned short* klo = khi + (size_t)16384 * 1024;

  unsigned short* WaTh = (unsigned short*)(alignf + 32505856);
  unsigned short* WaTl = WaTh + (size_t)1024 * 1024;

  const size_t ENCT_B   = (size_t)8 * 1024 * 2048 * 2;
  const size_t ALIGNB_B = (size_t)8 * 2048 * 2048 * 2;
  const size_t DECP_B   = (size_t)8 * 2048 * 1024 * 2;
  bool has_encT   = ws_size >= ENCT_B;
  bool has_alignb = ws_size >= ENCT_B + ALIGNB_B;
  bool has_decp   = ws_size >= ENCT_B + ALIGNB_B + 2 * DECP_B;
  unsigned short* encT   = (unsigned short*)d_ws;
  unsigned short* alignb = (unsigned short*)((char*)d_ws + ENCT_B);
  unsigned short* dech   = (unsigned short*)((char*)d_ws + ENCT_B + ALIGNB_B);
  unsigned short* decl   = (unsigned short*)((char*)d_ws + ENCT_B + ALIGNB_B + DECP_B);

  transpose_prep<true><<<dim3(16, 16, 1), 256, 0, stream>>>(
      Wa, 0, 1024, WaTh, WaTl, 0, 1024);
  if (has_encT)
    transpose_prep<false><<<dim3(32, 16, 8), 256, 0, stream>>>(
        enc, (size_t)2048 * 1024, 1024, encT, nullptr, (size_t)1024 * 2048, 2048);
  if (has_decp)
    split_prep<<<dim3(16384), 256, 0, stream>>>(dec, dech, decl);

  keys_gemm<<<dim3(8, 128), 256, 0, stream>>>(enc, WaTh, WaTl, bias, khi, klo);

  if (has_decp){
    gemm_big<3><<<512, 512, 0, stream>>>(
        dech, decl, khi, klo, 1024, 1024, 8, 8, 16,
        (size_t)2048 * 1024, (size_t)2048 * 1024, scores, 2048, (size_t)2048 * 2048);
    softmax_k<true><<<dim3(16384), 256, 0, stream>>>(scores, alignb);
    gemm_big<1><<<256, 512, 0, stream>>>(
        alignb, alignb, encT, encT, 2048, 2048, 8, 4, 32,
        (size_t)2048 * 2048, (size_t)1024 * 2048, ctx, 1024, (size_t)2048 * 1024);
  } else if (has_alignb){
    score_gemm<false><<<dim3(16, 16, 8), 256, 0, stream>>>(dec, nullptr, nullptr, khi, klo, scores);
    softmax_k<true><<<dim3(16384), 256, 0, stream>>>(scores, alignb);
    ctx_gemm_fast<<<dim3(1024), 256, 0, stream>>>(alignb, encT, ctx);
  } else {
    score_gemm<false><<<dim3(16, 16, 8), 256, 0, stream>>>(dec, nullptr, nullptr, khi, klo, scores);
    softmax_k<false><<<dim3(16384), 256, 0, stream>>>(scores, nullptr);
    if (has_encT)
      ctx_gemm<true><<<dim3(8, 16, 8), 256, 0, stream>>>(alignf, nullptr, encT, ctx);
    else
      ctx_gemm<false><<<dim3(8, 16, 8), 256, 0, stream>>>(alignf, enc, nullptr, ctx);
  }
}